// Round 6
// baseline (583.571 us; speedup 1.0000x reference)
//
#include <hip/hip_runtime.h>
#include <math.h>

typedef unsigned short ushort_t;
typedef unsigned int uint_t;
typedef short short8 __attribute__((ext_vector_type(8)));
typedef float float4a __attribute__((ext_vector_type(4)));
typedef uint_t uint4a __attribute__((ext_vector_type(4)));
typedef uint_t uint2a __attribute__((ext_vector_type(2)));

#define B_SZ 4
#define S_SZ 2048
#define E_SZ 1024
#define H_SZ 16
#define HD_SZ 64

#if __has_builtin(__builtin_amdgcn_exp2f)
#define EXP2F(x) __builtin_amdgcn_exp2f(x)
#else
#define EXP2F(x) exp2f(x)
#endif

// ---- helpers ----
__device__ __forceinline__ ushort_t f2bf(float f) {
    uint_t u = __builtin_bit_cast(uint_t, f);
    u = (u + 0x7fff + ((u >> 16) & 1)) >> 16;
    return (ushort_t)u;
}
// pack 2 fp32 -> 2 bf16 (round half-up) in one v_perm_b32
__device__ __forceinline__ uint_t pk_bf16(float a, float b) {
    uint_t ua = __builtin_bit_cast(uint_t, a) + 0x8000u;
    uint_t ub = __builtin_bit_cast(uint_t, b) + 0x8000u;
#if __has_builtin(__builtin_amdgcn_perm)
    return __builtin_amdgcn_perm(ub, ua, 0x07060302u);
#else
    return (ua >> 16) | (ub & 0xffff0000u);
#endif
}
__device__ __forceinline__ void async_copy16(const void* g, void* l) {
    __builtin_amdgcn_global_load_lds(
        (const __attribute__((address_space(1))) void*)g,
        (__attribute__((address_space(3))) void*)l, 16, 0, 0);
}

// ---- kernel 1: transpose 4 fp32 weight matrices (E x E) -> bf16 ----
__global__ __launch_bounds__(256) void transpose4(
    const float* __restrict__ W0, const float* __restrict__ W1,
    const float* __restrict__ W2, const float* __restrict__ W3,
    ushort_t* __restrict__ out)
{
    const float* src;
    switch (blockIdx.z) {
        case 0: src = W0; break;
        case 1: src = W1; break;
        case 2: src = W2; break;
        default: src = W3; break;
    }
    ushort_t* dst = out + (size_t)blockIdx.z * (E_SZ * E_SZ);
    __shared__ ushort_t t[32][33];
    int x = blockIdx.x * 32 + threadIdx.x;
    int y0 = blockIdx.y * 32;
    for (int i = threadIdx.y; i < 32; i += 8)
        t[i][threadIdx.x] = f2bf(src[(size_t)(y0 + i) * E_SZ + x]);
    __syncthreads();
    int yy = blockIdx.x * 32;
    int xx = y0 + threadIdx.x;
    for (int i = threadIdx.y; i < 32; i += 8)
        dst[(size_t)(yy + i) * E_SZ + xx] = t[threadIdx.x][i];
}

// ---- kernel 1b: bulk fp32 -> bf16 convert of query/key/value ----
// 8M elems per tensor; 8 elems/thread; grid (4096, 3).
__global__ __launch_bounds__(256) void cvt3(
    const float* __restrict__ s0, const float* __restrict__ s1,
    const float* __restrict__ s2, ushort_t* __restrict__ d0,
    ushort_t* __restrict__ d1, ushort_t* __restrict__ d2)
{
    const float* s; ushort_t* d;
    switch (blockIdx.y) {
        case 0: s = s0; d = d0; break;
        case 1: s = s1; d = d1; break;
        default: s = s2; d = d2; break;
    }
    size_t i = ((size_t)blockIdx.x * 256 + threadIdx.x) * 8;
    float4a u0 = *(const float4a*)(s + i);
    float4a u1 = *(const float4a*)(s + i + 4);
    uint4a w = (uint4a){pk_bf16(u0[0], u0[1]), pk_bf16(u0[2], u0[3]),
                        pk_bf16(u1[0], u1[1]), pk_bf16(u1[2], u1[3])};
    *(uint4a*)(d + i) = w;
}

// ---- GEMM core: Y[m,n] = sum_k X[m,k] * Wt[n,k] + bias[n] ----
// M=8192, N=K=1024. 128x128 tile, BK=64, 4 waves (2x2 of 64x64).
// X bf16, pure global_load_lds staging. LDS 32 KB.
// OUTF32: Y fp32 [M,N]. Else bf16: mode 0 -> [M,N], mode 1 -> [B,E,S].
template<bool OUTF32>
__device__ __forceinline__ void gemm_body(
    const ushort_t* X, const ushort_t* Wt, const float* bias,
    void* Yv, int mode, int tileM, int tileN)
{
    __shared__ __align__(16) ushort_t As[8192];  // [g(8)][row(128)][8]
    __shared__ __align__(16) ushort_t Bs[8192];
    const int tid = threadIdx.x;
    const int lane = tid & 63;
    const int quad = lane >> 4;
    const int l15 = lane & 15;
    const int wid = tid >> 6;
    const int wm = (wid >> 1) * 64;
    const int wn = (wid & 1) * 64;

    float4a acc[4][4];
    for (int i = 0; i < 4; i++)
        for (int j = 0; j < 4; j++)
            acc[i][j] = (float4a){0.f, 0.f, 0.f, 0.f};

    const ushort_t* Xa[4];
    const ushort_t* Wa[4];
    for (int p = 0; p < 4; p++) {
        int L = p * 256 + tid;
        int g = L >> 7, r = L & 127;
        Xa[p] = X + (size_t)(tileM + r) * E_SZ + g * 8;
        Wa[p] = Wt + (size_t)(tileN + r) * E_SZ + g * 8;
    }

    for (int k0 = 0; k0 < E_SZ; k0 += 64) {
        for (int p = 0; p < 4; p++) {
            int L = p * 256 + tid;
            async_copy16(Xa[p] + k0, &As[L * 8]);
            async_copy16(Wa[p] + k0, &Bs[L * 8]);
        }
        __syncthreads();
        for (int kk = 0; kk < 2; kk++) {
            short8 a[4], b[4];
            for (int mt = 0; mt < 4; mt++)
                a[mt] = *(const short8*)&As[(kk * 4 + quad) * 1024 + (wm + mt * 16 + l15) * 8];
            for (int nt = 0; nt < 4; nt++)
                b[nt] = *(const short8*)&Bs[(kk * 4 + quad) * 1024 + (wn + nt * 16 + l15) * 8];
            for (int mt = 0; mt < 4; mt++)
                for (int nt = 0; nt < 4; nt++)
                    acc[mt][nt] = __builtin_amdgcn_mfma_f32_16x16x32_bf16(
                        a[mt], b[nt], acc[mt][nt], 0, 0, 0);
        }
        __syncthreads();
    }

    for (int nt = 0; nt < 4; nt++) {
        int n = tileN + wn + nt * 16 + l15;
        float bv = bias[n];
        for (int mt = 0; mt < 4; mt++) {
            for (int r = 0; r < 4; r++) {
                int m = tileM + wm + mt * 16 + quad * 4 + r;
                float v = acc[mt][nt][r] + bv;
                if constexpr (OUTF32) {
                    ((float*)Yv)[(size_t)m * E_SZ + n] = v;
                } else {
                    ushort_t* Y = (ushort_t*)Yv;
                    if (mode == 0) {
                        Y[(size_t)m * E_SZ + n] = f2bf(v);
                    } else {
                        int bb = m >> 11, s = m & 2047;
                        Y[((size_t)(bb * E_SZ + n)) * S_SZ + s] = f2bf(v);
                    }
                }
            }
        }
    }
}

// fused Q/K/V projections: z selects input/weight/bias/output.
__global__ __launch_bounds__(256) void proj3(
    const ushort_t* __restrict__ x0, const ushort_t* __restrict__ x1,
    const ushort_t* __restrict__ x2, const ushort_t* __restrict__ Wt,
    const float* __restrict__ b0, const float* __restrict__ b1,
    const float* __restrict__ b2, ushort_t* __restrict__ y0,
    ushort_t* __restrict__ y1, ushort_t* __restrict__ y2)
{
    const ushort_t* X; const float* bias; ushort_t* Y; int mode = 0;
    switch (blockIdx.z) {
        case 0: X = x0; bias = b0; Y = y0; break;
        case 1: X = x1; bias = b1; Y = y1; break;
        default: X = x2; bias = b2; Y = y2; mode = 1; break;
    }
    gemm_body<false>(X, Wt + (size_t)blockIdx.z * E_SZ * E_SZ, bias, Y, mode,
                     blockIdx.y * 128, blockIdx.x * 128);
}

// final output projection: bf16 X -> fp32 Y
__global__ __launch_bounds__(256) void gemm_out(
    const ushort_t* __restrict__ X, const ushort_t* __restrict__ Wt,
    const float* __restrict__ bias, float* __restrict__ Y)
{
    gemm_body<true>(X, Wt, bias, Y, 0, blockIdx.y * 128, blockIdx.x * 128);
}

// ---- kernel 3: flash attention (all operands bf16, ws-resident) ----
// Q,K in [B,S,E]. V in [B,E,S] (transposed). Block: 128 q rows per (b,h),
// 4 waves x 32 q rows. S^T = K.Q^T (C-layout row=kidx, col=q).
// FIXED-max softmax: p = exp2(raw*CE - 11.5416) == exp(s_scaled - 8).
// Softmax is scale-invariant; scaled scores ~N(0,1), max ~6.2 << 8, and
// overflow needs raw > 770 (impossible) -> no running max, no rescale.
// P^T perm-packed to bf16, XOR-swizzled LDS round-trip; O^T = V^T.P^T.
__global__ __launch_bounds__(256) void attn(
    const ushort_t* __restrict__ Q, const ushort_t* __restrict__ K,
    const ushort_t* __restrict__ V, ushort_t* __restrict__ ctx)
{
    // PQ: Qs [8][128][8] (8192) at kt==0, then Ps swizzled [128][128]
    __shared__ __align__(16) ushort_t smem[32768];   // 64 KB
    ushort_t* PQ = smem;
    ushort_t* Ks = smem + 16384;         // [g(8)][row(128)][8]
    ushort_t* Vt = smem + 24576;         // swizzled [d(64)][c(128)]

    const int tid = threadIdx.x;
    const int lane = tid & 63;
    const int quad = lane >> 4;
    const int l15 = lane & 15;
    const int wid = tid >> 6;
    const int qt = blockIdx.x;              // 0..15
    const int bh = blockIdx.y;              // 0..63
    const int b = bh >> 4, h = bh & 15;
    const int s0 = qt * 128;
    const int wq = wid * 32;
    const float CE = 0.18033688011f;        // 0.125 * log2(e)
    const float MC = 11.5415601f;           // 8 * log2(e) (fixed max, scaled m=8)

    // stage Q once (completion covered by first in-loop barrier)
    for (int p = 0; p < 4; p++) {
        int L = p * 256 + tid;
        int g = L >> 7, r = L & 127;
        const ushort_t* src = Q + ((size_t)(b * S_SZ + s0 + r)) * E_SZ + h * HD_SZ + g * 8;
        async_copy16(src, &PQ[L * 8]);
    }

    float4a st[8][2];       // S^T acc: mt over kidx(8 x16), nt over q(2 x16)
    float4a o[4][2];        // O^T acc: mt over d(4 x16), nt over q(2 x16)
    for (int mt = 0; mt < 4; mt++)
        for (int nt = 0; nt < 2; nt++)
            o[mt][nt] = (float4a){0.f, 0.f, 0.f, 0.f};
    float lrow[2] = {0.f, 0.f};
    short8 qf[2][2];

    for (int kt = 0; kt < 16; kt++) {
        // stage K tile (async, lane-consecutive 16B)
        for (int p = 0; p < 4; p++) {
            int L = p * 256 + tid;
            int g = L >> 7, r = L & 127;
            const ushort_t* src = K + ((size_t)(b * S_SZ + kt * 128 + r)) * E_SZ + h * HD_SZ + g * 8;
            async_copy16(src, &Ks[L * 8]);
        }
        // stage V^T tile (swizzled rows of 128)
        for (int p = 0; p < 4; p++) {
            int c = p * 256 + tid;
            int d = c >> 4, cc = c & 15;
            const ushort_t* src = V + ((size_t)(b * E_SZ + h * HD_SZ + d)) * S_SZ + kt * 128 + cc * 8;
            short8 val = *(const short8*)src;
            *(short8*)&Vt[d * 128 + ((cc ^ (d & 7)) << 3)] = val;
        }
        __syncthreads();
        if (kt == 0) {
            for (int ks = 0; ks < 2; ks++)
                for (int nt = 0; nt < 2; nt++)
                    qf[ks][nt] = *(const short8*)&PQ[(ks * 4 + quad) * 1024 + (wq + nt * 16 + l15) * 8];
            __syncthreads();   // Ps writes below alias Qs; wait for all qf loads
        }

        // S^T[kidx][q] = sum_d K[kidx][d] * Q[q][d]
        for (int mt = 0; mt < 8; mt++)
            for (int nt = 0; nt < 2; nt++)
                st[mt][nt] = (float4a){0.f, 0.f, 0.f, 0.f};
        for (int ks = 0; ks < 2; ks++) {
            for (int mt = 0; mt < 8; mt++) {
                short8 kf = *(const short8*)&Ks[(ks * 4 + quad) * 1024 + (mt * 16 + l15) * 8];
                for (int nt = 0; nt < 2; nt++)
                    st[mt][nt] = __builtin_amdgcn_mfma_f32_16x16x32_bf16(
                        kf, qf[ks][nt], st[mt][nt], 0, 0, 0);
            }
        }

        // fixed-max softmax: p = exp2(raw*CE - MC); row-sum; pack; store
        float rsum[2] = {0.f, 0.f};
        for (int mt = 0; mt < 8; mt++)
            for (int nt = 0; nt < 2; nt++) {
                float e0 = EXP2F(fmaf(st[mt][nt][0], CE, -MC));
                float e1 = EXP2F(fmaf(st[mt][nt][1], CE, -MC));
                float e2 = EXP2F(fmaf(st[mt][nt][2], CE, -MC));
                float e3 = EXP2F(fmaf(st[mt][nt][3], CE, -MC));
                rsum[nt] += (e0 + e1) + (e2 + e3);
                uint2a pp = (uint2a){pk_bf16(e0, e1), pk_bf16(e2, e3)};
                int row = wq + nt * 16 + l15;
                *(uint2a*)&PQ[row * 128 + (((2 * mt + (quad >> 1)) ^ (row & 7)) << 3) + (quad & 1) * 4] = pp;
            }
        for (int nt = 0; nt < 2; nt++) {
            rsum[nt] += __shfl_xor(rsum[nt], 16);
            rsum[nt] += __shfl_xor(rsum[nt], 32);
            lrow[nt] += rsum[nt];
        }

        // O^T[d][q] += sum_kidx V^T[d][kidx] * P^T[kidx][q]  (16x16x32)
        for (int kk = 0; kk < 4; kk++) {
            int swz = ((kk * 4 + quad) ^ (l15 & 7)) << 3;
            short8 a[4], pb[2];
            for (int mt = 0; mt < 4; mt++)
                a[mt] = *(const short8*)&Vt[(mt * 16 + l15) * 128 + swz];
            for (int nt = 0; nt < 2; nt++)
                pb[nt] = *(const short8*)&PQ[(wq + nt * 16 + l15) * 128 + swz];
            for (int mt = 0; mt < 4; mt++)
                for (int nt = 0; nt < 2; nt++)
                    o[mt][nt] = __builtin_amdgcn_mfma_f32_16x16x32_bf16(
                        a[mt], pb[nt], o[mt][nt], 0, 0, 0);
        }
        __syncthreads();
    }

    // epilogue: ctx[b, s, h*64+d] = O^T[d][q] / l[q]   (8B packed stores)
    for (int nt = 0; nt < 2; nt++) {
        float inv = 1.f / lrow[nt];
        int s = s0 + wq + nt * 16 + l15;
        size_t base = ((size_t)(b * S_SZ + s)) * E_SZ + h * HD_SZ;
        for (int mt = 0; mt < 4; mt++) {
            int d = mt * 16 + quad * 4;
            uint2a w = (uint2a){pk_bf16(o[mt][nt][0] * inv, o[mt][nt][1] * inv),
                                pk_bf16(o[mt][nt][2] * inv, o[mt][nt][3] * inv)};
            *(uint2a*)&ctx[base + d] = w;
        }
    }
}

extern "C" void kernel_launch(void* const* d_in, const int* in_sizes, int n_in,
                              void* d_out, int out_size, void* d_ws, size_t ws_size,
                              hipStream_t stream) {
    const float* q_in = (const float*)d_in[0];
    const float* k_in = (const float*)d_in[1];
    const float* v_in = (const float*)d_in[2];
    const float* Wq = (const float*)d_in[3];
    const float* bq = (const float*)d_in[4];
    const float* Wk = (const float*)d_in[5];
    const float* bk = (const float*)d_in[6];
    const float* Wv = (const float*)d_in[7];
    const float* bv = (const float*)d_in[8];
    const float* Wo = (const float*)d_in[9];
    const float* bo = (const float*)d_in[10];

    ushort_t* ws = (ushort_t*)d_ws;
    const size_t WMAT = (size_t)E_SZ * E_SZ;           // 1M elements
    const size_t TEN = (size_t)B_SZ * S_SZ * E_SZ;     // 8M elements
    ushort_t* Wt = ws;                 // 4 transposed bf16 weights (8 MB)
    ushort_t* qb = ws + 4 * WMAT;      // bf16 copies of inputs
    ushort_t* kb = qb + TEN;
    ushort_t* vb = kb + TEN;
    ushort_t* qp = vb + TEN;           // projected Q/K/V
    ushort_t* kp = qp + TEN;
    ushort_t* vp = kp + TEN;           // stored [B, E, S]
    ushort_t* cx = qb;                 // ctx aliases qb (dead after proj3)

    transpose4<<<dim3(32, 32, 4), dim3(32, 8), 0, stream>>>(Wq, Wk, Wv, Wo, Wt);
    cvt3<<<dim3(4096, 3), 256, 0, stream>>>(q_in, k_in, v_in, qb, kb, vb);
    proj3<<<dim3(8, 64, 3), 256, 0, stream>>>(qb, kb, vb, Wt, bq, bk, bv, qp, kp, vp);
    attn<<<dim3(16, 64), 256, 0, stream>>>(qp, kp, vp, cx);
    gemm_out<<<dim3(8, 64), 256, 0, stream>>>(cx, Wt + 3 * WMAT, bo, (float*)d_out);
}

// Round 7
// 472.258 us; speedup vs baseline: 1.2357x; 1.2357x over previous
//
#include <hip/hip_runtime.h>
#include <math.h>

typedef unsigned short ushort_t;
typedef unsigned int uint_t;
typedef short short8 __attribute__((ext_vector_type(8)));
typedef float float4a __attribute__((ext_vector_type(4)));
typedef uint_t uint4a __attribute__((ext_vector_type(4)));
typedef uint_t uint2a __attribute__((ext_vector_type(2)));

#define B_SZ 4
#define S_SZ 2048
#define E_SZ 1024
#define H_SZ 16
#define HD_SZ 64

#if __has_builtin(__builtin_amdgcn_exp2f)
#define EXP2F(x) __builtin_amdgcn_exp2f(x)
#else
#define EXP2F(x) exp2f(x)
#endif

// ---- helpers ----
__device__ __forceinline__ ushort_t f2bf(float f) {
    uint_t u = __builtin_bit_cast(uint_t, f);
    u = (u + 0x7fff + ((u >> 16) & 1)) >> 16;
    return (ushort_t)u;
}
// pack 2 fp32 -> 2 bf16 (round half-up) in one v_perm_b32
__device__ __forceinline__ uint_t pk_bf16(float a, float b) {
    uint_t ua = __builtin_bit_cast(uint_t, a) + 0x8000u;
    uint_t ub = __builtin_bit_cast(uint_t, b) + 0x8000u;
#if __has_builtin(__builtin_amdgcn_perm)
    return __builtin_amdgcn_perm(ub, ua, 0x07060302u);
#else
    return (ua >> 16) | (ub & 0xffff0000u);
#endif
}
__device__ __forceinline__ void async_copy16(const void* g, void* l) {
    __builtin_amdgcn_global_load_lds(
        (const __attribute__((address_space(1))) void*)g,
        (__attribute__((address_space(3))) void*)l, 16, 0, 0);
}

// ---- kernel 1: transpose 4 fp32 weight matrices (E x E) -> bf16 ----
__global__ __launch_bounds__(256) void transpose4(
    const float* __restrict__ W0, const float* __restrict__ W1,
    const float* __restrict__ W2, const float* __restrict__ W3,
    ushort_t* __restrict__ out)
{
    const float* src;
    switch (blockIdx.z) {
        case 0: src = W0; break;
        case 1: src = W1; break;
        case 2: src = W2; break;
        default: src = W3; break;
    }
    ushort_t* dst = out + (size_t)blockIdx.z * (E_SZ * E_SZ);
    __shared__ ushort_t t[32][33];
    int x = blockIdx.x * 32 + threadIdx.x;
    int y0 = blockIdx.y * 32;
    for (int i = threadIdx.y; i < 32; i += 8)
        t[i][threadIdx.x] = f2bf(src[(size_t)(y0 + i) * E_SZ + x]);
    __syncthreads();
    int yy = blockIdx.x * 32;
    int xx = y0 + threadIdx.x;
    for (int i = threadIdx.y; i < 32; i += 8)
        dst[(size_t)(yy + i) * E_SZ + xx] = t[threadIdx.x][i];
}

// ---- kernel 1b: bulk fp32 -> bf16 convert of query/key/value ----
// 8M elems per tensor; 8 elems/thread; grid (4096, 3).
__global__ __launch_bounds__(256) void cvt3(
    const float* __restrict__ s0, const float* __restrict__ s1,
    const float* __restrict__ s2, ushort_t* __restrict__ d0,
    ushort_t* __restrict__ d1, ushort_t* __restrict__ d2)
{
    const float* s; ushort_t* d;
    switch (blockIdx.y) {
        case 0: s = s0; d = d0; break;
        case 1: s = s1; d = d1; break;
        default: s = s2; d = d2; break;
    }
    size_t i = ((size_t)blockIdx.x * 256 + threadIdx.x) * 8;
    float4a u0 = *(const float4a*)(s + i);
    float4a u1 = *(const float4a*)(s + i + 4);
    uint4a w = (uint4a){pk_bf16(u0[0], u0[1]), pk_bf16(u0[2], u0[3]),
                        pk_bf16(u1[0], u1[1]), pk_bf16(u1[2], u1[3])};
    *(uint4a*)(d + i) = w;
}

// ---- GEMM core: Y[m,n] = sum_k X[m,k] * Wt[n,k] + bias[n] ----
// M=8192, N=K=1024. 128x128 tile, BK=64, 4 waves (2x2 of 64x64).
// X bf16, pure global_load_lds staging. LDS 32 KB.
// OUTF32: Y fp32 [M,N]. Else bf16: mode 0 -> [M,N], mode 1 -> [B,E,S].
template<bool OUTF32>
__device__ __forceinline__ void gemm_body(
    const ushort_t* X, const ushort_t* Wt, const float* bias,
    void* Yv, int mode, int tileM, int tileN)
{
    __shared__ __align__(16) ushort_t As[8192];  // [g(8)][row(128)][8]
    __shared__ __align__(16) ushort_t Bs[8192];
    const int tid = threadIdx.x;
    const int lane = tid & 63;
    const int quad = lane >> 4;
    const int l15 = lane & 15;
    const int wid = tid >> 6;
    const int wm = (wid >> 1) * 64;
    const int wn = (wid & 1) * 64;

    float4a acc[4][4];
    for (int i = 0; i < 4; i++)
        for (int j = 0; j < 4; j++)
            acc[i][j] = (float4a){0.f, 0.f, 0.f, 0.f};

    const ushort_t* Xa[4];
    const ushort_t* Wa[4];
    for (int p = 0; p < 4; p++) {
        int L = p * 256 + tid;
        int g = L >> 7, r = L & 127;
        Xa[p] = X + (size_t)(tileM + r) * E_SZ + g * 8;
        Wa[p] = Wt + (size_t)(tileN + r) * E_SZ + g * 8;
    }

    for (int k0 = 0; k0 < E_SZ; k0 += 64) {
        for (int p = 0; p < 4; p++) {
            int L = p * 256 + tid;
            async_copy16(Xa[p] + k0, &As[L * 8]);
            async_copy16(Wa[p] + k0, &Bs[L * 8]);
        }
        __syncthreads();
        for (int kk = 0; kk < 2; kk++) {
            short8 a[4], b[4];
            for (int mt = 0; mt < 4; mt++)
                a[mt] = *(const short8*)&As[(kk * 4 + quad) * 1024 + (wm + mt * 16 + l15) * 8];
            for (int nt = 0; nt < 4; nt++)
                b[nt] = *(const short8*)&Bs[(kk * 4 + quad) * 1024 + (wn + nt * 16 + l15) * 8];
            for (int mt = 0; mt < 4; mt++)
                for (int nt = 0; nt < 4; nt++)
                    acc[mt][nt] = __builtin_amdgcn_mfma_f32_16x16x32_bf16(
                        a[mt], b[nt], acc[mt][nt], 0, 0, 0);
        }
        __syncthreads();
    }

    for (int nt = 0; nt < 4; nt++) {
        int n = tileN + wn + nt * 16 + l15;
        float bv = bias[n];
        for (int mt = 0; mt < 4; mt++) {
            for (int r = 0; r < 4; r++) {
                int m = tileM + wm + mt * 16 + quad * 4 + r;
                float v = acc[mt][nt][r] + bv;
                if constexpr (OUTF32) {
                    ((float*)Yv)[(size_t)m * E_SZ + n] = v;
                } else {
                    ushort_t* Y = (ushort_t*)Yv;
                    if (mode == 0) {
                        Y[(size_t)m * E_SZ + n] = f2bf(v);
                    } else {
                        int bb = m >> 11, s = m & 2047;
                        Y[((size_t)(bb * E_SZ + n)) * S_SZ + s] = f2bf(v);
                    }
                }
            }
        }
    }
}

// fused Q/K/V projections: z selects input/weight/bias/output.
__global__ __launch_bounds__(256) void proj3(
    const ushort_t* __restrict__ x0, const ushort_t* __restrict__ x1,
    const ushort_t* __restrict__ x2, const ushort_t* __restrict__ Wt,
    const float* __restrict__ b0, const float* __restrict__ b1,
    const float* __restrict__ b2, ushort_t* __restrict__ y0,
    ushort_t* __restrict__ y1, ushort_t* __restrict__ y2)
{
    const ushort_t* X; const float* bias; ushort_t* Y; int mode = 0;
    switch (blockIdx.z) {
        case 0: X = x0; bias = b0; Y = y0; break;
        case 1: X = x1; bias = b1; Y = y1; break;
        default: X = x2; bias = b2; Y = y2; mode = 1; break;
    }
    gemm_body<false>(X, Wt + (size_t)blockIdx.z * E_SZ * E_SZ, bias, Y, mode,
                     blockIdx.y * 128, blockIdx.x * 128);
}

// final output projection: bf16 X -> fp32 Y
__global__ __launch_bounds__(256) void gemm_out(
    const ushort_t* __restrict__ X, const ushort_t* __restrict__ Wt,
    const float* __restrict__ bias, float* __restrict__ Y)
{
    gemm_body<true>(X, Wt, bias, Y, 0, blockIdx.y * 128, blockIdx.x * 128);
}

// ---- kernel 3: flash attention (round-5 version: online softmax) ----
// Q,K in [B,S,E]. V in [B,E,S] (transposed). Block: 128 q rows per (b,h),
// 4 waves x 32 q rows. S^T = K.Q^T (C-layout row=kidx, col=q); softmax in
// exp2 domain (scale folded into one FMA); P^T packed to bf16 via
// v_perm_b32 and round-tripped through XOR-swizzled LDS; O^T = V^T.P^T.
// NOTE: round-6 fixed-max variant removed the rescale chain but pushed
// VGPR 116->136, crossing the 128-VGPR occupancy step (2->1 blocks/CU,
// 141->252 us). Keep this version's register footprint intact.
__global__ __launch_bounds__(256) void attn(
    const ushort_t* __restrict__ Q, const ushort_t* __restrict__ K,
    const ushort_t* __restrict__ V, ushort_t* __restrict__ ctx)
{
    // PQ: Qs [8][128][8] (8192) at kt==0, then Ps swizzled [128][128]
    __shared__ __align__(16) ushort_t smem[32768];   // 64 KB
    ushort_t* PQ = smem;
    ushort_t* Ks = smem + 16384;         // [g(8)][row(128)][8]
    ushort_t* Vt = smem + 24576;         // swizzled [d(64)][c(128)]

    const int tid = threadIdx.x;
    const int lane = tid & 63;
    const int quad = lane >> 4;
    const int l15 = lane & 15;
    const int wid = tid >> 6;
    const int qt = blockIdx.x;              // 0..15
    const int bh = blockIdx.y;              // 0..63
    const int b = bh >> 4, h = bh & 15;
    const int s0 = qt * 128;
    const int wq = wid * 32;
    const float CE = 0.18033688011f;        // 0.125 * log2(e)

    // stage Q once (completion covered by first in-loop barrier)
    for (int p = 0; p < 4; p++) {
        int L = p * 256 + tid;
        int g = L >> 7, r = L & 127;
        const ushort_t* src = Q + ((size_t)(b * S_SZ + s0 + r)) * E_SZ + h * HD_SZ + g * 8;
        async_copy16(src, &PQ[L * 8]);
    }

    float4a st[8][2];       // S^T acc: mt over kidx(8 x16), nt over q(2 x16)
    float4a o[4][2];        // O^T acc: mt over d(4 x16), nt over q(2 x16)
    for (int mt = 0; mt < 4; mt++)
        for (int nt = 0; nt < 2; nt++)
            o[mt][nt] = (float4a){0.f, 0.f, 0.f, 0.f};
    float mrow[2] = {-1e30f, -1e30f};   // raw-score units
    float lrow[2] = {0.f, 0.f};
    short8 qf[2][2];

    for (int kt = 0; kt < 16; kt++) {
        // stage K tile (async, lane-consecutive 16B)
        for (int p = 0; p < 4; p++) {
            int L = p * 256 + tid;
            int g = L >> 7, r = L & 127;
            const ushort_t* src = K + ((size_t)(b * S_SZ + kt * 128 + r)) * E_SZ + h * HD_SZ + g * 8;
            async_copy16(src, &Ks[L * 8]);
        }
        // stage V^T tile (swizzled rows of 128)
        for (int p = 0; p < 4; p++) {
            int c = p * 256 + tid;
            int d = c >> 4, cc = c & 15;
            const ushort_t* src = V + ((size_t)(b * E_SZ + h * HD_SZ + d)) * S_SZ + kt * 128 + cc * 8;
            short8 val = *(const short8*)src;
            *(short8*)&Vt[d * 128 + ((cc ^ (d & 7)) << 3)] = val;
        }
        __syncthreads();
        if (kt == 0) {
            for (int ks = 0; ks < 2; ks++)
                for (int nt = 0; nt < 2; nt++)
                    qf[ks][nt] = *(const short8*)&PQ[(ks * 4 + quad) * 1024 + (wq + nt * 16 + l15) * 8];
            __syncthreads();   // Ps writes below alias Qs; wait for all qf loads
        }

        // S^T[kidx][q] = sum_d K[kidx][d] * Q[q][d]
        for (int mt = 0; mt < 8; mt++)
            for (int nt = 0; nt < 2; nt++)
                st[mt][nt] = (float4a){0.f, 0.f, 0.f, 0.f};
        for (int ks = 0; ks < 2; ks++) {
            for (int mt = 0; mt < 8; mt++) {
                short8 kf = *(const short8*)&Ks[(ks * 4 + quad) * 1024 + (mt * 16 + l15) * 8];
                for (int nt = 0; nt < 2; nt++)
                    st[mt][nt] = __builtin_amdgcn_mfma_f32_16x16x32_bf16(
                        kf, qf[ks][nt], st[mt][nt], 0, 0, 0);
            }
        }

        // online softmax on raw scores; exp via exp2(st*CE - m*CE)
        float rmax[2] = {-1e30f, -1e30f};
        for (int mt = 0; mt < 8; mt++)
            for (int nt = 0; nt < 2; nt++)
                for (int r = 0; r < 4; r++)
                    rmax[nt] = fmaxf(rmax[nt], st[mt][nt][r]);
        for (int nt = 0; nt < 2; nt++) {
            rmax[nt] = fmaxf(rmax[nt], __shfl_xor(rmax[nt], 16));
            rmax[nt] = fmaxf(rmax[nt], __shfl_xor(rmax[nt], 32));
        }
        float alpha[2], mc[2], rsum[2] = {0.f, 0.f};
        for (int nt = 0; nt < 2; nt++) {
            float mn = fmaxf(mrow[nt], rmax[nt]);
            alpha[nt] = EXP2F((mrow[nt] - mn) * CE);
            mrow[nt] = mn;
            mc[nt] = mn * CE;
        }
        // exp, row-sum, perm-pack to bf16, swizzled LDS write (b64).
        // Each wave touches only its own q rows -> no barrier needed.
        for (int mt = 0; mt < 8; mt++)
            for (int nt = 0; nt < 2; nt++) {
                float e0 = EXP2F(fmaf(st[mt][nt][0], CE, -mc[nt]));
                float e1 = EXP2F(fmaf(st[mt][nt][1], CE, -mc[nt]));
                float e2 = EXP2F(fmaf(st[mt][nt][2], CE, -mc[nt]));
                float e3 = EXP2F(fmaf(st[mt][nt][3], CE, -mc[nt]));
                rsum[nt] += (e0 + e1) + (e2 + e3);
                uint2a pp = (uint2a){pk_bf16(e0, e1), pk_bf16(e2, e3)};
                int row = wq + nt * 16 + l15;
                // element col = mt*16 + quad*4 -> grp = 2mt + (quad>>1)
                *(uint2a*)&PQ[row * 128 + (((2 * mt + (quad >> 1)) ^ (row & 7)) << 3) + (quad & 1) * 4] = pp;
            }
        for (int nt = 0; nt < 2; nt++) {
            rsum[nt] += __shfl_xor(rsum[nt], 16);
            rsum[nt] += __shfl_xor(rsum[nt], 32);
            lrow[nt] = lrow[nt] * alpha[nt] + rsum[nt];
        }
        for (int mt = 0; mt < 4; mt++)
            for (int nt = 0; nt < 2; nt++)
                for (int r = 0; r < 4; r++)
                    o[mt][nt][r] *= alpha[nt];

        // O^T[d][q] += sum_kidx V^T[d][kidx] * P^T[kidx][q]  (16x16x32)
        for (int kk = 0; kk < 4; kk++) {
            int swz = ((kk * 4 + quad) ^ (l15 & 7)) << 3;   // row&7 == l15&7 for all rows used
            short8 a[4], pb[2];
            for (int mt = 0; mt < 4; mt++)
                a[mt] = *(const short8*)&Vt[(mt * 16 + l15) * 128 + swz];
            for (int nt = 0; nt < 2; nt++)
                pb[nt] = *(const short8*)&PQ[(wq + nt * 16 + l15) * 128 + swz];
            for (int mt = 0; mt < 4; mt++)
                for (int nt = 0; nt < 2; nt++)
                    o[mt][nt] = __builtin_amdgcn_mfma_f32_16x16x32_bf16(
                        a[mt], pb[nt], o[mt][nt], 0, 0, 0);
        }
        __syncthreads();
    }

    // epilogue: ctx[b, s, h*64+d] = O^T[d][q] / l[q]   (8B packed stores)
    for (int nt = 0; nt < 2; nt++) {
        float inv = 1.f / lrow[nt];
        int s = s0 + wq + nt * 16 + l15;
        size_t base = ((size_t)(b * S_SZ + s)) * E_SZ + h * HD_SZ;
        for (int mt = 0; mt < 4; mt++) {
            int d = mt * 16 + quad * 4;
            uint2a w = (uint2a){pk_bf16(o[mt][nt][0] * inv, o[mt][nt][1] * inv),
                                pk_bf16(o[mt][nt][2] * inv, o[mt][nt][3] * inv)};
            *(uint2a*)&ctx[base + d] = w;
        }
    }
}

extern "C" void kernel_launch(void* const* d_in, const int* in_sizes, int n_in,
                              void* d_out, int out_size, void* d_ws, size_t ws_size,
                              hipStream_t stream) {
    const float* q_in = (const float*)d_in[0];
    const float* k_in = (const float*)d_in[1];
    const float* v_in = (const float*)d_in[2];
    const float* Wq = (const float*)d_in[3];
    const float* bq = (const float*)d_in[4];
    const float* Wk = (const float*)d_in[5];
    const float* bk = (const float*)d_in[6];
    const float* Wv = (const float*)d_in[7];
    const float* bv = (const float*)d_in[8];
    const float* Wo = (const float*)d_in[9];
    const float* bo = (const float*)d_in[10];

    ushort_t* ws = (ushort_t*)d_ws;
    const size_t WMAT = (size_t)E_SZ * E_SZ;           // 1M elements
    const size_t TEN = (size_t)B_SZ * S_SZ * E_SZ;     // 8M elements
    ushort_t* Wt = ws;                 // 4 transposed bf16 weights (8 MB)
    ushort_t* qb = ws + 4 * WMAT;      // bf16 copies of inputs
    ushort_t* kb = qb + TEN;
    ushort_t* vb = kb + TEN;
    ushort_t* qp = vb + TEN;           // projected Q/K/V
    ushort_t* kp = qp + TEN;
    ushort_t* vp = kp + TEN;           // stored [B, E, S]
    ushort_t* cx = qb;                 // ctx aliases qb (dead after proj3)

    transpose4<<<dim3(32, 32, 4), dim3(32, 8), 0, stream>>>(Wq, Wk, Wv, Wo, Wt);
    cvt3<<<dim3(4096, 3), 256, 0, stream>>>(q_in, k_in, v_in, qb, kb, vb);
    proj3<<<dim3(8, 64, 3), 256, 0, stream>>>(qb, kb, vb, Wt, bq, bk, bv, qp, kp, vp);
    attn<<<dim3(16, 64), 256, 0, stream>>>(qp, kp, vp, cx);
    gemm_out<<<dim3(8, 64), 256, 0, stream>>>(cx, Wt + 3 * WMAT, bo, (float*)d_out);
}